// Round 6
// baseline (9150.471 us; speedup 1.0000x reference)
//
#include <hip/hip_runtime.h>
#include <math.h>

#define NN 48
#define MD 56

__device__ __forceinline__ float rcp_f(float x){
#if __has_builtin(__builtin_amdgcn_rcpf)
  return __builtin_amdgcn_rcpf(x);
#else
  return 1.0f/x;
#endif
}

// ---------------- main kernel: deg/A build + M1..M4 + gsum ----------------
// One block per item; 256 threads; LDS ~40KB -> 4 blocks/CU.
// All fp chains bit-identical to R5 (twice-validated numerics).
__global__ __launch_bounds__(256, 4)
void policy_fwd(const int* __restrict__ Nmat, const float* __restrict__ adj,
                const float* __restrict__ W1, const float* __restrict__ b1,
                const float* __restrict__ W2, const float* __restrict__ b2,
                const float* __restrict__ agg_sW, const float* __restrict__ agg_sb,
                const float* __restrict__ agg_tW, const float* __restrict__ agg_tb,
                const float* __restrict__ l1W, const float* __restrict__ l1b,
                const float* __restrict__ l2W, const float* __restrict__ l2b,
                const float* __restrict__ f1, const float* __restrict__ f2,
                const float* __restrict__ s1, const float* __restrict__ s2,
                const float* __restrict__ e1, const float* __restrict__ e2,
                const float* __restrict__ t1W, const float* __restrict__ t1b,
                const float* __restrict__ t2W, const float* __restrict__ t2b,
                const float* __restrict__ v1W, const float* __restrict__ v1b,
                const float* __restrict__ v2W, const float* __restrict__ v2b,
                const float* __restrict__ v3W, const float* __restrict__ v3b,
                float* __restrict__ gsumW,    // non-null => tail kernel handles rest
                float* __restrict__ out)
{
  __shared__ __align__(16) float sA[NN*48];    // A row-major, stride 48
  __shared__ __align__(16) float sHB[3264];    // h col-block / h_out / (fallback sT); deg at [3104..3248)
  __shared__ __align__(16) float sH2[3264];    // h2 (48x68); later M4 ch1 partials
  __shared__ __align__(16) float sEP[1280];    // embT[9][128]; later ch0 partials + gsum[128]
  __shared__ int   sNi[MD];

  const int b   = blockIdx.x;
  const int tid = threadIdx.x;
  const float* adjB = adj + (size_t)b * (3*NN*NN);
  float* sDeg = &sHB[3104];

  if (tid < MD) sNi[tid] = Nmat[b*MD + tid];

  // ---- degrees (exact div) ----
  {
    const int lane = tid & 15, grp = tid >> 4;
    for (int p = 0; p < 9; ++p) {
      const int row = p*16 + grp;
      const float* rp = adjB + row*NN;
      float s = rp[lane] + rp[lane+16] + rp[lane+32];
      s += __shfl_down(s, 8, 16);
      s += __shfl_down(s, 4, 16);
      s += __shfl_down(s, 2, 16);
      s += __shfl_down(s, 1, 16);
      if (lane == 0) sDeg[row] = 1.0f/(s + 1.0f);
    }
  }
  for (int o = tid; o < 1152; o += 256) sEP[o] = W1[o] + b1[o & 127];
  __syncthreads();

  // ---- A ----
  for (int o = tid; o < NN*NN; o += 256) {
    const int i = o / NN, j = o - i*NN;
    const float v = adjB[i*NN + j]          * sDeg[i]
                  + adjB[(NN + i)*NN + j]   * sDeg[NN + i]
                  + adjB[(2*NN + i)*NN + j] * sDeg[2*NN + i];
    sA[i*48 + j] = v;
  }
  __syncthreads();

  const int i2 = (tid >> 4)*3, d2 = (tid & 15)*4;

  // ---- M1+M2 fused, two 64-col rounds; chains identical to R5 ----
  float acc2[3][4] = {};
  #pragma unroll
  for (int r = 0; r < 2; ++r) {
    const int dg = r*64 + d2;
    // M1 with chunk-4 LDS prefetch
    {
      float acc[3][4] = {};
      float4 bv[4];
      #pragma unroll
      for (int u = 0; u < 4; ++u) bv[u] = *(const float4*)&sEP[sNi[u]*128 + dg];
      for (int c = 0; c < 11; ++c) {
        float4 bn[4];
        #pragma unroll
        for (int u = 0; u < 4; ++u) bn[u] = *(const float4*)&sEP[sNi[(c+1)*4+u]*128 + dg];
        #pragma unroll
        for (int u = 0; u < 4; ++u) {
          const int k = c*4 + u;
          const float a0 = sA[i2*48 + k], a1 = sA[(i2+1)*48 + k], a2 = sA[(i2+2)*48 + k];
          acc[0][0]=fmaf(a0,bv[u].x,acc[0][0]); acc[0][1]=fmaf(a0,bv[u].y,acc[0][1]);
          acc[0][2]=fmaf(a0,bv[u].z,acc[0][2]); acc[0][3]=fmaf(a0,bv[u].w,acc[0][3]);
          acc[1][0]=fmaf(a1,bv[u].x,acc[1][0]); acc[1][1]=fmaf(a1,bv[u].y,acc[1][1]);
          acc[1][2]=fmaf(a1,bv[u].z,acc[1][2]); acc[1][3]=fmaf(a1,bv[u].w,acc[1][3]);
          acc[2][0]=fmaf(a2,bv[u].x,acc[2][0]); acc[2][1]=fmaf(a2,bv[u].y,acc[2][1]);
          acc[2][2]=fmaf(a2,bv[u].z,acc[2][2]); acc[2][3]=fmaf(a2,bv[u].w,acc[2][3]);
        }
        #pragma unroll
        for (int u = 0; u < 4; ++u) bv[u] = bn[u];
      }
      #pragma unroll
      for (int u = 0; u < 4; ++u) {
        const int k = 44 + u;
        const float a0 = sA[i2*48 + k], a1 = sA[(i2+1)*48 + k], a2 = sA[(i2+2)*48 + k];
        acc[0][0]=fmaf(a0,bv[u].x,acc[0][0]); acc[0][1]=fmaf(a0,bv[u].y,acc[0][1]);
        acc[0][2]=fmaf(a0,bv[u].z,acc[0][2]); acc[0][3]=fmaf(a0,bv[u].w,acc[0][3]);
        acc[1][0]=fmaf(a1,bv[u].x,acc[1][0]); acc[1][1]=fmaf(a1,bv[u].y,acc[1][1]);
        acc[1][2]=fmaf(a1,bv[u].z,acc[1][2]); acc[1][3]=fmaf(a1,bv[u].w,acc[1][3]);
        acc[2][0]=fmaf(a2,bv[u].x,acc[2][0]); acc[2][1]=fmaf(a2,bv[u].y,acc[2][1]);
        acc[2][2]=fmaf(a2,bv[u].z,acc[2][2]); acc[2][3]=fmaf(a2,bv[u].w,acc[2][3]);
      }
      #pragma unroll
      for (int ii = 0; ii < 3; ++ii) {
        const float4 rv = *(const float4*)&sEP[sNi[i2+ii]*128 + dg];
        float4 o;
        o.x = tanhf(acc[ii][0] + rv.x);
        o.y = tanhf(acc[ii][1] + rv.y);
        o.z = tanhf(acc[ii][2] + rv.z);
        o.w = tanhf(acc[ii][3] + rv.w);
        *(float4*)&sHB[(i2+ii)*68 + d2] = o;
      }
    }
    __syncthreads();
    // M2 accumulate with chunk-8 global prefetch
    {
      const float* W2r = W2 + r*4096;
      float4 wb[8];
      #pragma unroll
      for (int u = 0; u < 8; ++u) wb[u] = *(const float4*)&W2r[u*64 + d2];
      for (int c = 0; c < 7; ++c) {
        float4 wn[8];
        #pragma unroll
        for (int u = 0; u < 8; ++u) wn[u] = *(const float4*)&W2r[((c+1)*8+u)*64 + d2];
        #pragma unroll
        for (int u = 0; u < 8; ++u) {
          const int k = c*8 + u;
          const float a0 = sHB[i2*68 + k], a1 = sHB[(i2+1)*68 + k], a2 = sHB[(i2+2)*68 + k];
          acc2[0][0]=fmaf(a0,wb[u].x,acc2[0][0]); acc2[0][1]=fmaf(a0,wb[u].y,acc2[0][1]);
          acc2[0][2]=fmaf(a0,wb[u].z,acc2[0][2]); acc2[0][3]=fmaf(a0,wb[u].w,acc2[0][3]);
          acc2[1][0]=fmaf(a1,wb[u].x,acc2[1][0]); acc2[1][1]=fmaf(a1,wb[u].y,acc2[1][1]);
          acc2[1][2]=fmaf(a1,wb[u].z,acc2[1][2]); acc2[1][3]=fmaf(a1,wb[u].w,acc2[1][3]);
          acc2[2][0]=fmaf(a2,wb[u].x,acc2[2][0]); acc2[2][1]=fmaf(a2,wb[u].y,acc2[2][1]);
          acc2[2][2]=fmaf(a2,wb[u].z,acc2[2][2]); acc2[2][3]=fmaf(a2,wb[u].w,acc2[2][3]);
        }
        #pragma unroll
        for (int u = 0; u < 8; ++u) wb[u] = wn[u];
      }
      #pragma unroll
      for (int u = 0; u < 8; ++u) {
        const int k = 56 + u;
        const float a0 = sHB[i2*68 + k], a1 = sHB[(i2+1)*68 + k], a2 = sHB[(i2+2)*68 + k];
        acc2[0][0]=fmaf(a0,wb[u].x,acc2[0][0]); acc2[0][1]=fmaf(a0,wb[u].y,acc2[0][1]);
        acc2[0][2]=fmaf(a0,wb[u].z,acc2[0][2]); acc2[0][3]=fmaf(a0,wb[u].w,acc2[0][3]);
        acc2[1][0]=fmaf(a1,wb[u].x,acc2[1][0]); acc2[1][1]=fmaf(a1,wb[u].y,acc2[1][1]);
        acc2[1][2]=fmaf(a1,wb[u].z,acc2[1][2]); acc2[1][3]=fmaf(a1,wb[u].w,acc2[1][3]);
        acc2[2][0]=fmaf(a2,wb[u].x,acc2[2][0]); acc2[2][1]=fmaf(a2,wb[u].y,acc2[2][1]);
        acc2[2][2]=fmaf(a2,wb[u].z,acc2[2][2]); acc2[2][3]=fmaf(a2,wb[u].w,acc2[2][3]);
      }
    }
    __syncthreads();
  }
  {
    const float4 bb = *(const float4*)&b2[d2];
    #pragma unroll
    for (int ii = 0; ii < 3; ++ii) {
      float4 o;
      o.x = acc2[ii][0] + bb.x; o.y = acc2[ii][1] + bb.y;
      o.z = acc2[ii][2] + bb.z; o.w = acc2[ii][3] + bb.w;
      *(float4*)&sH2[(i2+ii)*68 + d2] = o;
    }
  }
  __syncthreads();

  // ---- M3 with chunk-4 LDS prefetch ----
  {
    float acc[3][4] = {};
    float4 bv[4];
    #pragma unroll
    for (int u = 0; u < 4; ++u) bv[u] = *(const float4*)&sH2[u*68 + d2];
    for (int c = 0; c < 11; ++c) {
      float4 bn[4];
      #pragma unroll
      for (int u = 0; u < 4; ++u) bn[u] = *(const float4*)&sH2[((c+1)*4+u)*68 + d2];
      #pragma unroll
      for (int u = 0; u < 4; ++u) {
        const int k = c*4 + u;
        const float a0 = sA[i2*48 + k], a1 = sA[(i2+1)*48 + k], a2 = sA[(i2+2)*48 + k];
        acc[0][0]=fmaf(a0,bv[u].x,acc[0][0]); acc[0][1]=fmaf(a0,bv[u].y,acc[0][1]);
        acc[0][2]=fmaf(a0,bv[u].z,acc[0][2]); acc[0][3]=fmaf(a0,bv[u].w,acc[0][3]);
        acc[1][0]=fmaf(a1,bv[u].x,acc[1][0]); acc[1][1]=fmaf(a1,bv[u].y,acc[1][1]);
        acc[1][2]=fmaf(a1,bv[u].z,acc[1][2]); acc[1][3]=fmaf(a1,bv[u].w,acc[1][3]);
        acc[2][0]=fmaf(a2,bv[u].x,acc[2][0]); acc[2][1]=fmaf(a2,bv[u].y,acc[2][1]);
        acc[2][2]=fmaf(a2,bv[u].z,acc[2][2]); acc[2][3]=fmaf(a2,bv[u].w,acc[2][3]);
      }
      #pragma unroll
      for (int u = 0; u < 4; ++u) bv[u] = bn[u];
    }
    #pragma unroll
    for (int u = 0; u < 4; ++u) {
      const int k = 44 + u;
      const float a0 = sA[i2*48 + k], a1 = sA[(i2+1)*48 + k], a2 = sA[(i2+2)*48 + k];
      acc[0][0]=fmaf(a0,bv[u].x,acc[0][0]); acc[0][1]=fmaf(a0,bv[u].y,acc[0][1]);
      acc[0][2]=fmaf(a0,bv[u].z,acc[0][2]); acc[0][3]=fmaf(a0,bv[u].w,acc[0][3]);
      acc[1][0]=fmaf(a1,bv[u].x,acc[1][0]); acc[1][1]=fmaf(a1,bv[u].y,acc[1][1]);
      acc[1][2]=fmaf(a1,bv[u].z,acc[1][2]); acc[1][3]=fmaf(a1,bv[u].w,acc[1][3]);
      acc[2][0]=fmaf(a2,bv[u].x,acc[2][0]); acc[2][1]=fmaf(a2,bv[u].y,acc[2][1]);
      acc[2][2]=fmaf(a2,bv[u].z,acc[2][2]); acc[2][3]=fmaf(a2,bv[u].w,acc[2][3]);
    }
    #pragma unroll
    for (int ii = 0; ii < 3; ++ii) {
      const float4 rv = *(const float4*)&sH2[(i2+ii)*68 + d2];
      float4 o;
      o.x = tanhf(acc[ii][0] + rv.x);
      o.y = tanhf(acc[ii][1] + rv.y);
      o.z = tanhf(acc[ii][2] + rv.z);
      o.w = tanhf(acc[ii][3] + rv.w);
      *(float4*)&sHB[(i2+ii)*68 + d2] = o;
    }
  }
  __syncthreads();   // h_out in sHB; sH2, sEP dead

  // ---- M4: two channel passes, chunk-4 dual-stream prefetch ----
  #pragma unroll
  for (int ch = 0; ch < 2; ++ch) {
    float as[3][4] = {}, at_[3][4] = {};
    const float* baseS = agg_sW + ch*64 + d2;
    const float* baseT = agg_tW + ch*64 + d2;
    float4 cs[4], ct[4];
    #pragma unroll
    for (int u = 0; u < 4; ++u) { cs[u] = *(const float4*)&baseS[u*128]; ct[u] = *(const float4*)&baseT[u*128]; }
    for (int c = 0; c < 15; ++c) {
      float4 ns[4], nt[4];
      #pragma unroll
      for (int u = 0; u < 4; ++u) {
        ns[u] = *(const float4*)&baseS[((c+1)*4+u)*128];
        nt[u] = *(const float4*)&baseT[((c+1)*4+u)*128];
      }
      #pragma unroll
      for (int u = 0; u < 4; ++u) {
        const int k = c*4 + u;
        const float a0 = sHB[i2*68 + k], a1 = sHB[(i2+1)*68 + k], a2 = sHB[(i2+2)*68 + k];
        as[0][0]=fmaf(a0,cs[u].x,as[0][0]); as[0][1]=fmaf(a0,cs[u].y,as[0][1]);
        as[0][2]=fmaf(a0,cs[u].z,as[0][2]); as[0][3]=fmaf(a0,cs[u].w,as[0][3]);
        as[1][0]=fmaf(a1,cs[u].x,as[1][0]); as[1][1]=fmaf(a1,cs[u].y,as[1][1]);
        as[1][2]=fmaf(a1,cs[u].z,as[1][2]); as[1][3]=fmaf(a1,cs[u].w,as[1][3]);
        as[2][0]=fmaf(a2,cs[u].x,as[2][0]); as[2][1]=fmaf(a2,cs[u].y,as[2][1]);
        as[2][2]=fmaf(a2,cs[u].z,as[2][2]); as[2][3]=fmaf(a2,cs[u].w,as[2][3]);
        at_[0][0]=fmaf(a0,ct[u].x,at_[0][0]); at_[0][1]=fmaf(a0,ct[u].y,at_[0][1]);
        at_[0][2]=fmaf(a0,ct[u].z,at_[0][2]); at_[0][3]=fmaf(a0,ct[u].w,at_[0][3]);
        at_[1][0]=fmaf(a1,ct[u].x,at_[1][0]); at_[1][1]=fmaf(a1,ct[u].y,at_[1][1]);
        at_[1][2]=fmaf(a1,ct[u].z,at_[1][2]); at_[1][3]=fmaf(a1,ct[u].w,at_[1][3]);
        at_[2][0]=fmaf(a2,ct[u].x,at_[2][0]); at_[2][1]=fmaf(a2,ct[u].y,at_[2][1]);
        at_[2][2]=fmaf(a2,ct[u].z,at_[2][2]); at_[2][3]=fmaf(a2,ct[u].w,at_[2][3]);
      }
      #pragma unroll
      for (int u = 0; u < 4; ++u) { cs[u] = ns[u]; ct[u] = nt[u]; }
    }
    #pragma unroll
    for (int u = 0; u < 4; ++u) {
      const int k = 60 + u;
      const float a0 = sHB[i2*68 + k], a1 = sHB[(i2+1)*68 + k], a2 = sHB[(i2+2)*68 + k];
      as[0][0]=fmaf(a0,cs[u].x,as[0][0]); as[0][1]=fmaf(a0,cs[u].y,as[0][1]);
      as[0][2]=fmaf(a0,cs[u].z,as[0][2]); as[0][3]=fmaf(a0,cs[u].w,as[0][3]);
      as[1][0]=fmaf(a1,cs[u].x,as[1][0]); as[1][1]=fmaf(a1,cs[u].y,as[1][1]);
      as[1][2]=fmaf(a1,cs[u].z,as[1][2]); as[1][3]=fmaf(a1,cs[u].w,as[1][3]);
      as[2][0]=fmaf(a2,cs[u].x,as[2][0]); as[2][1]=fmaf(a2,cs[u].y,as[2][1]);
      as[2][2]=fmaf(a2,cs[u].z,as[2][2]); as[2][3]=fmaf(a2,cs[u].w,as[2][3]);
      at_[0][0]=fmaf(a0,ct[u].x,at_[0][0]); at_[0][1]=fmaf(a0,ct[u].y,at_[0][1]);
      at_[0][2]=fmaf(a0,ct[u].z,at_[0][2]); at_[0][3]=fmaf(a0,ct[u].w,at_[0][3]);
      at_[1][0]=fmaf(a1,ct[u].x,at_[1][0]); at_[1][1]=fmaf(a1,ct[u].y,at_[1][1]);
      at_[1][2]=fmaf(a1,ct[u].z,at_[1][2]); at_[1][3]=fmaf(a1,ct[u].w,at_[1][3]);
      at_[2][0]=fmaf(a2,ct[u].x,at_[2][0]); at_[2][1]=fmaf(a2,ct[u].y,at_[2][1]);
      at_[2][2]=fmaf(a2,ct[u].z,at_[2][2]); at_[2][3]=fmaf(a2,ct[u].w,at_[2][3]);
    }
    // epilogue (order identical to R5: acc + gather + bias)
    float p[4] = {0.f,0.f,0.f,0.f};
    const float4 bsb = *(const float4*)&agg_sb[ch*64 + d2];
    const float4 btb = *(const float4*)&agg_tb[ch*64 + d2];
    const float bsba[4] = {bsb.x,bsb.y,bsb.z,bsb.w};
    const float btba[4] = {btb.x,btb.y,btb.z,btb.w};
    #pragma unroll
    for (int ii = 0; ii < 3; ++ii) {
      const int t = sNi[i2+ii];
      const float* gs = &agg_sW[(64 + t)*128 + ch*64];
      const float* gt = &agg_tW[(64 + t)*128 + ch*64];
      #pragma unroll
      for (int dd = 0; dd < 4; ++dd) {
        const float sg = 1.0f/(1.0f + expf(-(as[ii][dd] + gs[d2+dd] + bsba[dd])));
        const float tg = tanhf(at_[ii][dd] + gt[d2+dd] + btba[dd]);
        p[dd] = fmaf(sg, tg, p[dd]);
      }
    }
    const int grp = tid >> 4;
    if (ch == 0) *(float4*)&sEP[grp*64 + d2] = *(float4*)p;
    else         *(float4*)&sH2[grp*64 + d2] = *(float4*)p;
  }
  __syncthreads();
  if (tid < 64) {
    float s = 0.0f;
    #pragma unroll
    for (int g = 0; g < 16; ++g) s += sEP[g*64 + tid];
    sEP[1024 + tid] = s;
  } else if (tid < 128) {
    const int m = tid - 64;
    float s = 0.0f;
    #pragma unroll
    for (int g = 0; g < 16; ++g) s += sH2[g*64 + m];
    sEP[1024 + 64 + m] = s;
  }
  __syncthreads();

  if (gsumW != nullptr) {
    if (tid < 128) gsumW[(size_t)b*128 + tid] = sEP[1024 + tid];
    return;
  }

  // ---------------- fallback in-kernel tail (R5 verbatim) ----------------
  float* sT = sHB;
  const float* sGsum = &sEP[1024];
  if (tid < 128) sT[tid + 1024] = tanhf(sGsum[tid]);
  __syncthreads();
  if (tid < 128) {
    float a = l1b[tid];
    for (int k = 0; k < 128; ++k) a = fmaf(sT[1024+k], l1W[k*128 + tid], a);
    sT[1152 + tid] = a;
  }
  __syncthreads();
  if (tid < 64) {
    float a = l2b[tid];
    for (int k = 0; k < 128; ++k) a = fmaf(sT[1152+k], l2W[k*64 + tid], a);
    sT[1280 + tid] = a;
  }
  __syncthreads();
  if (tid < 160) {
    const int hh = tid >> 5, j = tid & 31;
    const float* Wp = (hh==0) ? f1 : (hh==1) ? s1 : (hh==2) ? e1 : (hh==3) ? t1W : v1W;
    float a = (hh==3) ? t1b[j] : (hh==4) ? v1b[j] : 0.0f;
    for (int k = 0; k < 64; ++k) a = fmaf(sT[1280+k], Wp[k*32 + j], a);
    sT[1344 + tid] = (a > 0.0f) ? a : 0.1f*a;
  }
  __syncthreads();
  if (tid < 56) {
    float a = 0.0f;
    for (int k = 0; k < 32; ++k) a = fmaf(sT[1344+k], f2[k*56 + tid], a);
    sT[1504 + tid] = a;
  } else if (tid < 112) {
    const int m = tid - 56; float a = 0.0f;
    for (int k = 0; k < 32; ++k) a = fmaf(sT[1376+k], s2[k*56 + m], a);
    sT[1560 + m] = a;
  } else if (tid < 115) {
    const int m = tid - 112; float a = 0.0f;
    for (int k = 0; k < 32; ++k) a = fmaf(sT[1408+k], e2[k*3 + m], a);
    sT[1616 + m] = a;
  } else if (tid < 117) {
    const int m = tid - 115; float a = t2b[m];
    for (int k = 0; k < 32; ++k) a = fmaf(sT[1440+k], t2W[k*2 + m], a);
    sT[1619 + m] = a;
  } else if (tid < 133) {
    const int m = tid - 117; float a = v2b[m];
    for (int k = 0; k < 32; ++k) a = fmaf(sT[1472+k], v2W[k*16 + m], a);
    sT[1624 + m] = (a > 0.0f) ? a : 0.1f*a;
  }
  __syncthreads();
  if (tid == 0) {
    float a = v3b[0];
    for (int k = 0; k < 16; ++k) a = fmaf(sT[1624+k], v3W[k], a);
    sT[1640] = a;
  }
  __syncthreads();
  if (tid < 64) {
    const int m = tid;
    const bool inb = (m < MD);
    const bool ex  = inb && (sNi[m] > 0) && (m < NN);
    const size_t ob = (size_t)b * 118;
    float lg1 = inb ? (sT[1504+m] + (ex ? 0.0f : -10000.0f)) : -INFINITY;
    float mv = lg1; int mi = inb ? m : 1000;
    #pragma unroll
    for (int off = 32; off > 0; off >>= 1) {
      const float ov = __shfl_down(mv, off);
      const int   oi = __shfl_down(mi, off);
      if (ov > mv || (ov == mv && oi < mi)) { mv = ov; mi = oi; }
    }
    mv = __shfl(mv, 0);
    const int first = __shfl(mi, 0);
    float ev = inb ? __expf(lg1 - mv) : 0.0f;
    float sum1 = ev;
    #pragma unroll
    for (int off = 32; off > 0; off >>= 1) sum1 += __shfl_down(sum1, off);
    sum1 = rcp_f(__shfl(sum1, 0));
    if (inb) out[ob + m] = ev * sum1;
    const bool m2 = inb && ((ex || m >= NN) && (m != first));
    float lg2 = inb ? (sT[1560+m] + (m2 ? 0.0f : -10000.0f)) : -INFINITY;
    float mv2 = lg2;
    #pragma unroll
    for (int off = 32; off > 0; off >>= 1) mv2 = fmaxf(mv2, __shfl_down(mv2, off));
    mv2 = __shfl(mv2, 0);
    float ev2 = inb ? __expf(lg2 - mv2) : 0.0f;
    float sum2 = ev2;
    #pragma unroll
    for (int off = 32; off > 0; off >>= 1) sum2 += __shfl_down(sum2, off);
    sum2 = rcp_f(__shfl(sum2, 0));
    if (inb) out[ob + 56 + m] = ev2 * sum2;
    if (m < 3) {
      const float x0 = sT[1616], x1 = sT[1617], x2 = sT[1618];
      const float mx = fmaxf(x0, fmaxf(x1, x2));
      const float q0 = __expf(x0-mx), q1 = __expf(x1-mx), q2 = __expf(x2-mx);
      out[ob + 112 + m] = ((m==0) ? q0 : (m==1) ? q1 : q2) / (q0+q1+q2);
    }
    if (m < 2) {
      const float x0 = sT[1619], x1 = sT[1620];
      const float mx = fmaxf(x0, x1);
      const float q0 = __expf(x0-mx), q1 = __expf(x1-mx);
      out[ob + 115 + m] = ((m==0) ? q0 : q1) / (q0+q1);
    }
    if (m == 0) out[ob + 117] = sT[1640];
  }
}

// ---------------- tail kernel: 1 wave per item ----------------
__global__ __launch_bounds__(64, 8)
void policy_tail(const int* __restrict__ Nmat, const float* __restrict__ gsumW,
                 const float* __restrict__ l1W, const float* __restrict__ l1b,
                 const float* __restrict__ l2W, const float* __restrict__ l2b,
                 const float* __restrict__ f1, const float* __restrict__ f2,
                 const float* __restrict__ s1, const float* __restrict__ s2,
                 const float* __restrict__ e1, const float* __restrict__ e2,
                 const float* __restrict__ t1W, const float* __restrict__ t1b,
                 const float* __restrict__ t2W, const float* __restrict__ t2b,
                 const float* __restrict__ v1W, const float* __restrict__ v1b,
                 const float* __restrict__ v2W, const float* __restrict__ v2b,
                 const float* __restrict__ v3W, const float* __restrict__ v3b,
                 float* __restrict__ out)
{
  __shared__ float sT[648];
  __shared__ int sNi[MD];
  const int b = blockIdx.x, l = threadIdx.x;

  if (l < MD) sNi[l] = Nmat[b*MD + l];
  sT[l]      = tanhf(gsumW[(size_t)b*128 + l]);       // g
  sT[64 + l] = tanhf(gsumW[(size_t)b*128 + 64 + l]);
  __syncthreads();
  #pragma unroll
  for (int h = 0; h < 2; ++h) {                        // a1: [128..256)
    const int j = h*64 + l;
    float a = l1b[j];
    for (int k = 0; k < 128; ++k) a = fmaf(sT[k], l1W[k*128 + j], a);
    sT[128 + j] = a;
  }
  __syncthreads();
  {                                                    // hfeat: [256..320)
    float a = l2b[l];
    for (int k = 0; k < 128; ++k) a = fmaf(sT[128+k], l2W[k*64 + l], a);
    sT[256 + l] = a;
  }
  __syncthreads();
  for (int base = 0; base < 6; base += 2) {            // 5 heads L1: [320..480)
    const int hh = base + (l >> 5), j = l & 31;
    if (hh < 5) {
      const float* Wp = (hh==0) ? f1 : (hh==1) ? s1 : (hh==2) ? e1 : (hh==3) ? t1W : v1W;
      float a = (hh==3) ? t1b[j] : (hh==4) ? v1b[j] : 0.0f;
      for (int k = 0; k < 64; ++k) a = fmaf(sT[256+k], Wp[k*32 + j], a);
      sT[320 + hh*32 + j] = (a > 0.0f) ? a : 0.1f*a;
    }
  }
  __syncthreads();
  if (l < 56) {                                        // out1: [480..536)
    float a = 0.0f;
    for (int k = 0; k < 32; ++k) a = fmaf(sT[320+k], f2[k*56 + l], a);
    sT[480 + l] = a;
  }
  if (l < 56) {                                        // out2: [536..592)
    float a = 0.0f;
    for (int k = 0; k < 32; ++k) a = fmaf(sT[352+k], s2[k*56 + l], a);
    sT[536 + l] = a;
  }
  if (l < 3) {                                         // oute: [592..595)
    float a = 0.0f;
    for (int k = 0; k < 32; ++k) a = fmaf(sT[384+k], e2[k*3 + l], a);
    sT[592 + l] = a;
  }
  if (l < 2) {                                         // outs: [595..597)
    float a = t2b[l];
    for (int k = 0; k < 32; ++k) a = fmaf(sT[416+k], t2W[k*2 + l], a);
    sT[595 + l] = a;
  }
  if (l < 16) {                                        // v2h: [600..616)
    float a = v2b[l];
    for (int k = 0; k < 32; ++k) a = fmaf(sT[448+k], v2W[k*16 + l], a);
    sT[600 + l] = (a > 0.0f) ? a : 0.1f*a;
  }
  __syncthreads();
  if (l == 0) {                                        // value: [616]
    float a = v3b[0];
    for (int k = 0; k < 16; ++k) a = fmaf(sT[600+k], v3W[k], a);
    sT[616] = a;
  }
  __syncthreads();

  {
    const int m = l;
    const bool inb = (m < MD);
    const bool ex  = inb && (sNi[m] > 0) && (m < NN);
    const size_t ob = (size_t)b * 118;
    float lg1 = inb ? (sT[480+m] + (ex ? 0.0f : -10000.0f)) : -INFINITY;
    float mv = lg1; int mi = inb ? m : 1000;
    #pragma unroll
    for (int off = 32; off > 0; off >>= 1) {
      const float ov = __shfl_down(mv, off);
      const int   oi = __shfl_down(mi, off);
      if (ov > mv || (ov == mv && oi < mi)) { mv = ov; mi = oi; }
    }
    mv = __shfl(mv, 0);
    const int first = __shfl(mi, 0);
    float ev = inb ? __expf(lg1 - mv) : 0.0f;
    float sum1 = ev;
    #pragma unroll
    for (int off = 32; off > 0; off >>= 1) sum1 += __shfl_down(sum1, off);
    sum1 = rcp_f(__shfl(sum1, 0));
    if (inb) out[ob + m] = ev * sum1;
    const bool m2 = inb && ((ex || m >= NN) && (m != first));
    float lg2 = inb ? (sT[536+m] + (m2 ? 0.0f : -10000.0f)) : -INFINITY;
    float mv2 = lg2;
    #pragma unroll
    for (int off = 32; off > 0; off >>= 1) mv2 = fmaxf(mv2, __shfl_down(mv2, off));
    mv2 = __shfl(mv2, 0);
    float ev2 = inb ? __expf(lg2 - mv2) : 0.0f;
    float sum2 = ev2;
    #pragma unroll
    for (int off = 32; off > 0; off >>= 1) sum2 += __shfl_down(sum2, off);
    sum2 = rcp_f(__shfl(sum2, 0));
    if (inb) out[ob + 56 + m] = ev2 * sum2;
    if (m < 3) {
      const float x0 = sT[592], x1 = sT[593], x2 = sT[594];
      const float mx = fmaxf(x0, fmaxf(x1, x2));
      const float q0 = __expf(x0-mx), q1 = __expf(x1-mx), q2 = __expf(x2-mx);
      out[ob + 112 + m] = ((m==0) ? q0 : (m==1) ? q1 : q2) / (q0+q1+q2);
    }
    if (m < 2) {
      const float x0 = sT[595], x1 = sT[596];
      const float mx = fmaxf(x0, x1);
      const float q0 = __expf(x0-mx), q1 = __expf(x1-mx);
      out[ob + 115 + m] = ((m==0) ? q0 : q1) / (q0+q1);
    }
    if (m == 0) out[ob + 117] = sT[616];
  }
}

extern "C" void kernel_launch(void* const* d_in, const int* in_sizes, int n_in,
                              void* d_out, int out_size, void* d_ws, size_t ws_size,
                              hipStream_t stream) {
  (void)n_in; (void)out_size;
  const int B = in_sizes[0] / MD;
  const bool split = (ws_size >= (size_t)B * 128 * sizeof(float));
  float* gsumW = split ? (float*)d_ws : nullptr;

  policy_fwd<<<dim3(B), dim3(256), 0, stream>>>(
      (const int*)d_in[0],  (const float*)d_in[1],
      (const float*)d_in[2],  (const float*)d_in[3],
      (const float*)d_in[4],  (const float*)d_in[5],
      (const float*)d_in[6],  (const float*)d_in[7],
      (const float*)d_in[8],  (const float*)d_in[9],
      (const float*)d_in[10], (const float*)d_in[11],
      (const float*)d_in[12], (const float*)d_in[13],
      (const float*)d_in[14], (const float*)d_in[15],
      (const float*)d_in[16], (const float*)d_in[17],
      (const float*)d_in[18], (const float*)d_in[19],
      (const float*)d_in[20], (const float*)d_in[21],
      (const float*)d_in[22], (const float*)d_in[23],
      (const float*)d_in[24], (const float*)d_in[25],
      (const float*)d_in[26], (const float*)d_in[27],
      (const float*)d_in[28], (const float*)d_in[29],
      gsumW, (float*)d_out);

  if (split) {
    policy_tail<<<dim3(B), dim3(64), 0, stream>>>(
        (const int*)d_in[0], (const float*)gsumW,
        (const float*)d_in[10], (const float*)d_in[11],
        (const float*)d_in[12], (const float*)d_in[13],
        (const float*)d_in[14], (const float*)d_in[15],
        (const float*)d_in[16], (const float*)d_in[17],
        (const float*)d_in[18], (const float*)d_in[19],
        (const float*)d_in[20], (const float*)d_in[21],
        (const float*)d_in[22], (const float*)d_in[23],
        (const float*)d_in[24], (const float*)d_in[25],
        (const float*)d_in[26], (const float*)d_in[27],
        (const float*)d_in[28], (const float*)d_in[29],
        (float*)d_out);
  }
}

// Round 7
// 7717.896 us; speedup vs baseline: 1.1856x; 1.1856x over previous
//
#include <hip/hip_runtime.h>
#include <math.h>

#define NN 48
#define MD 56

typedef float f32x2 __attribute__((ext_vector_type(2)));

#if __has_builtin(__builtin_elementwise_fma)
#define PKFMA(A,B,C) __builtin_elementwise_fma(A,B,C)
#else
__device__ __forceinline__ f32x2 PKFMA(f32x2 a, f32x2 b, f32x2 c){
  f32x2 r; r.x = fmaf(a.x,b.x,c.x); r.y = fmaf(a.y,b.y,c.y); return r;
}
#endif
#define ELEM(v,u) ((u)==0 ? (v).x : (u)==1 ? (v).y : (u)==2 ? (v).z : (v).w)

__device__ __forceinline__ float rcp_f(float x){
#if __has_builtin(__builtin_amdgcn_rcpf)
  return __builtin_amdgcn_rcpf(x);
#else
  return 1.0f/x;
#endif
}

// ---------------- main kernel: deg/A build + M1..M4 + gsum ----------------
// One block per item; 256 threads; LDS ~40KB -> 4 blocks/CU.
// All fp chains bit-identical to R5 (packed fma = same fp32 fma, same order).
__global__ __launch_bounds__(256, 4)
void policy_fwd(const int* __restrict__ Nmat, const float* __restrict__ adj,
                const float* __restrict__ W1, const float* __restrict__ b1,
                const float* __restrict__ W2, const float* __restrict__ b2,
                const float* __restrict__ agg_sW, const float* __restrict__ agg_sb,
                const float* __restrict__ agg_tW, const float* __restrict__ agg_tb,
                const float* __restrict__ l1W, const float* __restrict__ l1b,
                const float* __restrict__ l2W, const float* __restrict__ l2b,
                const float* __restrict__ f1, const float* __restrict__ f2,
                const float* __restrict__ s1, const float* __restrict__ s2,
                const float* __restrict__ e1, const float* __restrict__ e2,
                const float* __restrict__ t1W, const float* __restrict__ t1b,
                const float* __restrict__ t2W, const float* __restrict__ t2b,
                const float* __restrict__ v1W, const float* __restrict__ v1b,
                const float* __restrict__ v2W, const float* __restrict__ v2b,
                const float* __restrict__ v3W, const float* __restrict__ v3b,
                float* __restrict__ gsumW,    // non-null => tail kernel handles rest
                float* __restrict__ out)
{
  __shared__ __align__(16) float sA[NN*48];    // A row-major, stride 48
  __shared__ __align__(16) float sHB[3264];    // h col-block / h_out / (fallback sT); deg at [3104..3248)
  __shared__ __align__(16) float sH2[3264];    // h2 (48x68); later M4 ch1 partials
  __shared__ __align__(16) float sEP[1280];    // embT[9][128]; later ch0 partials + gsum[128]
  __shared__ int   sNi[MD];

  const int b   = blockIdx.x;
  const int tid = threadIdx.x;
  const float* adjB = adj + (size_t)b * (3*NN*NN);
  float* sDeg = &sHB[3104];

  if (tid < MD) sNi[tid] = Nmat[b*MD + tid];

  // ---- degrees (exact div) ----
  {
    const int lane = tid & 15, grp = tid >> 4;
    for (int p = 0; p < 9; ++p) {
      const int row = p*16 + grp;
      const float* rp = adjB + row*NN;
      float s = rp[lane] + rp[lane+16] + rp[lane+32];
      s += __shfl_down(s, 8, 16);
      s += __shfl_down(s, 4, 16);
      s += __shfl_down(s, 2, 16);
      s += __shfl_down(s, 1, 16);
      if (lane == 0) sDeg[row] = 1.0f/(s + 1.0f);
    }
  }
  for (int o = tid; o < 1152; o += 256) sEP[o] = W1[o] + b1[o & 127];
  __syncthreads();

  // ---- A ----
  for (int o = tid; o < NN*NN; o += 256) {
    const int i = o / NN, j = o - i*NN;
    const float v = adjB[i*NN + j]          * sDeg[i]
                  + adjB[(NN + i)*NN + j]   * sDeg[NN + i]
                  + adjB[(2*NN + i)*NN + j] * sDeg[2*NN + i];
    sA[i*48 + j] = v;
  }
  __syncthreads();

  const int i2 = (tid >> 4)*3, d2 = (tid & 15)*4;

  // ---- M1+M2 fused, two 64-col rounds; chains identical to R5 ----
  f32x2 q0a={0.f,0.f}, q0b={0.f,0.f}, q1a={0.f,0.f}, q1b={0.f,0.f},
        q2a={0.f,0.f}, q2b={0.f,0.f};                 // h2 accumulators (persistent)
  #pragma unroll
  for (int r = 0; r < 2; ++r) {
    const int dg = r*64 + d2;
    // ---- M1: h(i2..i2+2, dg..dg+3); A via ds_read_b128, packed fma ----
    {
      f32x2 p0a={0.f,0.f}, p0b={0.f,0.f}, p1a={0.f,0.f}, p1b={0.f,0.f},
            p2a={0.f,0.f}, p2b={0.f,0.f};
      for (int c = 0; c < 12; ++c) {
        const float4 av0 = *(const float4*)&sA[(i2  )*48 + c*4];
        const float4 av1 = *(const float4*)&sA[(i2+1)*48 + c*4];
        const float4 av2 = *(const float4*)&sA[(i2+2)*48 + c*4];
        #pragma unroll
        for (int u = 0; u < 4; ++u) {
          const float4 bv = *(const float4*)&sEP[sNi[c*4+u]*128 + dg];
          f32x2 bl; bl.x = bv.x; bl.y = bv.y;
          f32x2 bh; bh.x = bv.z; bh.y = bv.w;
          f32x2 A0; A0.x = A0.y = ELEM(av0,u);
          f32x2 A1; A1.x = A1.y = ELEM(av1,u);
          f32x2 A2; A2.x = A2.y = ELEM(av2,u);
          p0a = PKFMA(A0, bl, p0a); p0b = PKFMA(A0, bh, p0b);
          p1a = PKFMA(A1, bl, p1a); p1b = PKFMA(A1, bh, p1b);
          p2a = PKFMA(A2, bl, p2a); p2b = PKFMA(A2, bh, p2b);
        }
      }
      const float4 rv0 = *(const float4*)&sEP[sNi[i2  ]*128 + dg];
      const float4 rv1 = *(const float4*)&sEP[sNi[i2+1]*128 + dg];
      const float4 rv2 = *(const float4*)&sEP[sNi[i2+2]*128 + dg];
      float4 o0, o1, o2;
      o0.x = tanhf(p0a.x + rv0.x); o0.y = tanhf(p0a.y + rv0.y);
      o0.z = tanhf(p0b.x + rv0.z); o0.w = tanhf(p0b.y + rv0.w);
      o1.x = tanhf(p1a.x + rv1.x); o1.y = tanhf(p1a.y + rv1.y);
      o1.z = tanhf(p1b.x + rv1.z); o1.w = tanhf(p1b.y + rv1.w);
      o2.x = tanhf(p2a.x + rv2.x); o2.y = tanhf(p2a.y + rv2.y);
      o2.z = tanhf(p2b.x + rv2.z); o2.w = tanhf(p2b.y + rv2.w);
      *(float4*)&sHB[(i2  )*68 + d2] = o0;
      *(float4*)&sHB[(i2+1)*68 + d2] = o1;
      *(float4*)&sHB[(i2+2)*68 + d2] = o2;
    }
    __syncthreads();
    // ---- M2 accumulate: h2 += h[:,blk] @ W2[blk,:] ----
    {
      const float* W2r = W2 + r*4096;
      for (int c = 0; c < 16; ++c) {
        const float4 av0 = *(const float4*)&sHB[(i2  )*68 + c*4];
        const float4 av1 = *(const float4*)&sHB[(i2+1)*68 + c*4];
        const float4 av2 = *(const float4*)&sHB[(i2+2)*68 + c*4];
        #pragma unroll
        for (int u = 0; u < 4; ++u) {
          const float4 wv = *(const float4*)&W2r[(c*4+u)*64 + d2];
          f32x2 bl; bl.x = wv.x; bl.y = wv.y;
          f32x2 bh; bh.x = wv.z; bh.y = wv.w;
          f32x2 A0; A0.x = A0.y = ELEM(av0,u);
          f32x2 A1; A1.x = A1.y = ELEM(av1,u);
          f32x2 A2; A2.x = A2.y = ELEM(av2,u);
          q0a = PKFMA(A0, bl, q0a); q0b = PKFMA(A0, bh, q0b);
          q1a = PKFMA(A1, bl, q1a); q1b = PKFMA(A1, bh, q1b);
          q2a = PKFMA(A2, bl, q2a); q2b = PKFMA(A2, bh, q2b);
        }
      }
    }
    __syncthreads();
  }
  {
    const float4 bb = *(const float4*)&b2[d2];
    float4 o0, o1, o2;
    o0.x = q0a.x + bb.x; o0.y = q0a.y + bb.y; o0.z = q0b.x + bb.z; o0.w = q0b.y + bb.w;
    o1.x = q1a.x + bb.x; o1.y = q1a.y + bb.y; o1.z = q1b.x + bb.z; o1.w = q1b.y + bb.w;
    o2.x = q2a.x + bb.x; o2.y = q2a.y + bb.y; o2.z = q2b.x + bb.z; o2.w = q2b.y + bb.w;
    *(float4*)&sH2[(i2  )*68 + d2] = o0;
    *(float4*)&sH2[(i2+1)*68 + d2] = o1;
    *(float4*)&sH2[(i2+2)*68 + d2] = o2;
  }
  __syncthreads();

  // ---- M3: h_out = tanh(A@h2 + h2) -> sHB ----
  {
    f32x2 p0a={0.f,0.f}, p0b={0.f,0.f}, p1a={0.f,0.f}, p1b={0.f,0.f},
          p2a={0.f,0.f}, p2b={0.f,0.f};
    for (int c = 0; c < 12; ++c) {
      const float4 av0 = *(const float4*)&sA[(i2  )*48 + c*4];
      const float4 av1 = *(const float4*)&sA[(i2+1)*48 + c*4];
      const float4 av2 = *(const float4*)&sA[(i2+2)*48 + c*4];
      #pragma unroll
      for (int u = 0; u < 4; ++u) {
        const float4 bv = *(const float4*)&sH2[(c*4+u)*68 + d2];
        f32x2 bl; bl.x = bv.x; bl.y = bv.y;
        f32x2 bh; bh.x = bv.z; bh.y = bv.w;
        f32x2 A0; A0.x = A0.y = ELEM(av0,u);
        f32x2 A1; A1.x = A1.y = ELEM(av1,u);
        f32x2 A2; A2.x = A2.y = ELEM(av2,u);
        p0a = PKFMA(A0, bl, p0a); p0b = PKFMA(A0, bh, p0b);
        p1a = PKFMA(A1, bl, p1a); p1b = PKFMA(A1, bh, p1b);
        p2a = PKFMA(A2, bl, p2a); p2b = PKFMA(A2, bh, p2b);
      }
    }
    const float4 rv0 = *(const float4*)&sH2[(i2  )*68 + d2];
    const float4 rv1 = *(const float4*)&sH2[(i2+1)*68 + d2];
    const float4 rv2 = *(const float4*)&sH2[(i2+2)*68 + d2];
    float4 o0, o1, o2;
    o0.x = tanhf(p0a.x + rv0.x); o0.y = tanhf(p0a.y + rv0.y);
    o0.z = tanhf(p0b.x + rv0.z); o0.w = tanhf(p0b.y + rv0.w);
    o1.x = tanhf(p1a.x + rv1.x); o1.y = tanhf(p1a.y + rv1.y);
    o1.z = tanhf(p1b.x + rv1.z); o1.w = tanhf(p1b.y + rv1.w);
    o2.x = tanhf(p2a.x + rv2.x); o2.y = tanhf(p2a.y + rv2.y);
    o2.z = tanhf(p2b.x + rv2.z); o2.w = tanhf(p2b.y + rv2.w);
    *(float4*)&sHB[(i2  )*68 + d2] = o0;
    *(float4*)&sHB[(i2+1)*68 + d2] = o1;
    *(float4*)&sHB[(i2+2)*68 + d2] = o2;
  }
  __syncthreads();   // h_out in sHB; sH2, sEP dead

  // ---- M4: both channels in one k-pass (R5 structure), packed fma ----
  {
    f32x2 s0a[3], s0b[3], s1a[3], s1b[3], t0a[3], t0b[3], t1a[3], t1b[3];
    #pragma unroll
    for (int ii = 0; ii < 3; ++ii) {
      s0a[ii]=f32x2{0.f,0.f}; s0b[ii]=f32x2{0.f,0.f};
      s1a[ii]=f32x2{0.f,0.f}; s1b[ii]=f32x2{0.f,0.f};
      t0a[ii]=f32x2{0.f,0.f}; t0b[ii]=f32x2{0.f,0.f};
      t1a[ii]=f32x2{0.f,0.f}; t1b[ii]=f32x2{0.f,0.f};
    }
    for (int c = 0; c < 16; ++c) {
      const float4 av0 = *(const float4*)&sHB[(i2  )*68 + c*4];
      const float4 av1 = *(const float4*)&sHB[(i2+1)*68 + c*4];
      const float4 av2 = *(const float4*)&sHB[(i2+2)*68 + c*4];
      #pragma unroll
      for (int u = 0; u < 4; ++u) {
        const int k = c*4 + u;
        const float4 bs0 = *(const float4*)&agg_sW[k*128 + d2];
        const float4 bs1 = *(const float4*)&agg_sW[k*128 + 64 + d2];
        const float4 bt0 = *(const float4*)&agg_tW[k*128 + d2];
        const float4 bt1 = *(const float4*)&agg_tW[k*128 + 64 + d2];
        f32x2 s0l; s0l.x=bs0.x; s0l.y=bs0.y;  f32x2 s0h; s0h.x=bs0.z; s0h.y=bs0.w;
        f32x2 s1l; s1l.x=bs1.x; s1l.y=bs1.y;  f32x2 s1h; s1h.x=bs1.z; s1h.y=bs1.w;
        f32x2 t0l; t0l.x=bt0.x; t0l.y=bt0.y;  f32x2 t0h; t0h.x=bt0.z; t0h.y=bt0.w;
        f32x2 t1l; t1l.x=bt1.x; t1l.y=bt1.y;  f32x2 t1h; t1h.x=bt1.z; t1h.y=bt1.w;
        f32x2 A[3];
        A[0].x = A[0].y = ELEM(av0,u);
        A[1].x = A[1].y = ELEM(av1,u);
        A[2].x = A[2].y = ELEM(av2,u);
        #pragma unroll
        for (int ii = 0; ii < 3; ++ii) {
          s0a[ii] = PKFMA(A[ii], s0l, s0a[ii]); s0b[ii] = PKFMA(A[ii], s0h, s0b[ii]);
          s1a[ii] = PKFMA(A[ii], s1l, s1a[ii]); s1b[ii] = PKFMA(A[ii], s1h, s1b[ii]);
          t0a[ii] = PKFMA(A[ii], t0l, t0a[ii]); t0b[ii] = PKFMA(A[ii], t0h, t0b[ii]);
          t1a[ii] = PKFMA(A[ii], t1l, t1a[ii]); t1b[ii] = PKFMA(A[ii], t1h, t1b[ii]);
        }
      }
    }
    // epilogue (order identical to R5: acc + gather + bias; ch0 then ch1 per dd)
    float p0[4] = {0.f,0.f,0.f,0.f}, p1[4] = {0.f,0.f,0.f,0.f};
    const float4 bsb0 = *(const float4*)&agg_sb[d2];
    const float4 bsb1 = *(const float4*)&agg_sb[64 + d2];
    const float4 btb0 = *(const float4*)&agg_tb[d2];
    const float4 btb1 = *(const float4*)&agg_tb[64 + d2];
    #pragma unroll
    for (int ii = 0; ii < 3; ++ii) {
      const int t = sNi[i2+ii];
      const float* gs = &agg_sW[(64 + t)*128];
      const float* gt = &agg_tW[(64 + t)*128];
      #pragma unroll
      for (int dd = 0; dd < 4; ++dd) {
        const float as0 = (dd==0)?s0a[ii].x:(dd==1)?s0a[ii].y:(dd==2)?s0b[ii].x:s0b[ii].y;
        const float at0 = (dd==0)?t0a[ii].x:(dd==1)?t0a[ii].y:(dd==2)?t0b[ii].x:t0b[ii].y;
        const float as1 = (dd==0)?s1a[ii].x:(dd==1)?s1a[ii].y:(dd==2)?s1b[ii].x:s1b[ii].y;
        const float at1 = (dd==0)?t1a[ii].x:(dd==1)?t1a[ii].y:(dd==2)?t1b[ii].x:t1b[ii].y;
        const float sg0 = 1.0f/(1.0f + expf(-(as0 + gs[d2+dd]    + ELEM(bsb0,dd))));
        const float tg0 = tanhf(at0 + gt[d2+dd]    + ELEM(btb0,dd));
        p0[dd] = fmaf(sg0, tg0, p0[dd]);
        const float sg1 = 1.0f/(1.0f + expf(-(as1 + gs[64+d2+dd] + ELEM(bsb1,dd))));
        const float tg1 = tanhf(at1 + gt[64+d2+dd] + ELEM(btb1,dd));
        p1[dd] = fmaf(sg1, tg1, p1[dd]);
      }
    }
    const int grp = tid >> 4;
    *(float4*)&sEP[grp*64 + d2] = *(float4*)p0;   // ch0 partials (emb dead)
    *(float4*)&sH2[grp*64 + d2] = *(float4*)p1;   // ch1 partials (h2 dead)
  }
  __syncthreads();
  if (tid < 64) {
    float s = 0.0f;
    #pragma unroll
    for (int g = 0; g < 16; ++g) s += sEP[g*64 + tid];
    sEP[1024 + tid] = s;
  } else if (tid < 128) {
    const int m = tid - 64;
    float s = 0.0f;
    #pragma unroll
    for (int g = 0; g < 16; ++g) s += sH2[g*64 + m];
    sEP[1024 + 64 + m] = s;
  }
  __syncthreads();

  if (gsumW != nullptr) {
    if (tid < 128) gsumW[(size_t)b*128 + tid] = sEP[1024 + tid];
    return;
  }

  // ---------------- fallback in-kernel tail (R5 verbatim) ----------------
  float* sT = sHB;
  const float* sGsum = &sEP[1024];
  if (tid < 128) sT[tid + 1024] = tanhf(sGsum[tid]);
  __syncthreads();
  if (tid < 128) {
    float a = l1b[tid];
    for (int k = 0; k < 128; ++k) a = fmaf(sT[1024+k], l1W[k*128 + tid], a);
    sT[1152 + tid] = a;
  }
  __syncthreads();
  if (tid < 64) {
    float a = l2b[tid];
    for (int k = 0; k < 128; ++k) a = fmaf(sT[1152+k], l2W[k*64 + tid], a);
    sT[1280 + tid] = a;
  }
  __syncthreads();
  if (tid < 160) {
    const int hh = tid >> 5, j = tid & 31;
    const float* Wp = (hh==0) ? f1 : (hh==1) ? s1 : (hh==2) ? e1 : (hh==3) ? t1W : v1W;
    float a = (hh==3) ? t1b[j] : (hh==4) ? v1b[j] : 0.0f;
    for (int k = 0; k < 64; ++k) a = fmaf(sT[1280+k], Wp[k*32 + j], a);
    sT[1344 + tid] = (a > 0.0f) ? a : 0.1f*a;
  }
  __syncthreads();
  if (tid < 56) {
    float a = 0.0f;
    for (int k = 0; k < 32; ++k) a = fmaf(sT[1344+k], f2[k*56 + tid], a);
    sT[1504 + tid] = a;
  } else if (tid < 112) {
    const int m = tid - 56; float a = 0.0f;
    for (int k = 0; k < 32; ++k) a = fmaf(sT[1376+k], s2[k*56 + m], a);
    sT[1560 + m] = a;
  } else if (tid < 115) {
    const int m = tid - 112; float a = 0.0f;
    for (int k = 0; k < 32; ++k) a = fmaf(sT[1408+k], e2[k*3 + m], a);
    sT[1616 + m] = a;
  } else if (tid < 117) {
    const int m = tid - 115; float a = t2b[m];
    for (int k = 0; k < 32; ++k) a = fmaf(sT[1440+k], t2W[k*2 + m], a);
    sT[1619 + m] = a;
  } else if (tid < 133) {
    const int m = tid - 117; float a = v2b[m];
    for (int k = 0; k < 32; ++k) a = fmaf(sT[1472+k], v2W[k*16 + m], a);
    sT[1624 + m] = (a > 0.0f) ? a : 0.1f*a;
  }
  __syncthreads();
  if (tid == 0) {
    float a = v3b[0];
    for (int k = 0; k < 16; ++k) a = fmaf(sT[1624+k], v3W[k], a);
    sT[1640] = a;
  }
  __syncthreads();
  if (tid < 64) {
    const int m = tid;
    const bool inb = (m < MD);
    const bool ex  = inb && (sNi[m] > 0) && (m < NN);
    const size_t ob = (size_t)b * 118;
    float lg1 = inb ? (sT[1504+m] + (ex ? 0.0f : -10000.0f)) : -INFINITY;
    float mv = lg1; int mi = inb ? m : 1000;
    #pragma unroll
    for (int off = 32; off > 0; off >>= 1) {
      const float ov = __shfl_down(mv, off);
      const int   oi = __shfl_down(mi, off);
      if (ov > mv || (ov == mv && oi < mi)) { mv = ov; mi = oi; }
    }
    mv = __shfl(mv, 0);
    const int first = __shfl(mi, 0);
    float ev = inb ? __expf(lg1 - mv) : 0.0f;
    float sum1 = ev;
    #pragma unroll
    for (int off = 32; off > 0; off >>= 1) sum1 += __shfl_down(sum1, off);
    sum1 = rcp_f(__shfl(sum1, 0));
    if (inb) out[ob + m] = ev * sum1;
    const bool m2 = inb && ((ex || m >= NN) && (m != first));
    float lg2 = inb ? (sT[1560+m] + (m2 ? 0.0f : -10000.0f)) : -INFINITY;
    float mv2 = lg2;
    #pragma unroll
    for (int off = 32; off > 0; off >>= 1) mv2 = fmaxf(mv2, __shfl_down(mv2, off));
    mv2 = __shfl(mv2, 0);
    float ev2 = inb ? __expf(lg2 - mv2) : 0.0f;
    float sum2 = ev2;
    #pragma unroll
    for (int off = 32; off > 0; off >>= 1) sum2 += __shfl_down(sum2, off);
    sum2 = rcp_f(__shfl(sum2, 0));
    if (inb) out[ob + 56 + m] = ev2 * sum2;
    if (m < 3) {
      const float x0 = sT[1616], x1 = sT[1617], x2 = sT[1618];
      const float mx = fmaxf(x0, fmaxf(x1, x2));
      const float q0 = __expf(x0-mx), q1 = __expf(x1-mx), q2 = __expf(x2-mx);
      out[ob + 112 + m] = ((m==0) ? q0 : (m==1) ? q1 : q2) / (q0+q1+q2);
    }
    if (m < 2) {
      const float x0 = sT[1619], x1 = sT[1620];
      const float mx = fmaxf(x0, x1);
      const float q0 = __expf(x0-mx), q1 = __expf(x1-mx);
      out[ob + 115 + m] = ((m==0) ? q0 : q1) / (q0+q1);
    }
    if (m == 0) out[ob + 117] = sT[1640];
  }
}

// ---------------- tail kernel: 1 wave per item ----------------
__global__ __launch_bounds__(64, 8)
void policy_tail(const int* __restrict__ Nmat, const float* __restrict__ gsumW,
                 const float* __restrict__ l1W, const float* __restrict__ l1b,
                 const float* __restrict__ l2W, const float* __restrict__ l2b,
                 const float* __restrict__ f1, const float* __restrict__ f2,
                 const float* __restrict__ s1, const float* __restrict__ s2,
                 const float* __restrict__ e1, const float* __restrict__ e2,
                 const float* __restrict__ t1W, const float* __restrict__ t1b,
                 const float* __restrict__ t2W, const float* __restrict__ t2b,
                 const float* __restrict__ v1W, const float* __restrict__ v1b,
                 const float* __restrict__ v2W, const float* __restrict__ v2b,
                 const float* __restrict__ v3W, const float* __restrict__ v3b,
                 float* __restrict__ out)
{
  __shared__ float sT[648];
  __shared__ int sNi[MD];
  const int b = blockIdx.x, l = threadIdx.x;

  if (l < MD) sNi[l] = Nmat[b*MD + l];
  sT[l]      = tanhf(gsumW[(size_t)b*128 + l]);       // g
  sT[64 + l] = tanhf(gsumW[(size_t)b*128 + 64 + l]);
  __syncthreads();
  #pragma unroll
  for (int h = 0; h < 2; ++h) {                        // a1: [128..256)
    const int j = h*64 + l;
    float a = l1b[j];
    for (int k = 0; k < 128; ++k) a = fmaf(sT[k], l1W[k*128 + j], a);
    sT[128 + j] = a;
  }
  __syncthreads();
  {                                                    // hfeat: [256..320)
    float a = l2b[l];
    for (int k = 0; k < 128; ++k) a = fmaf(sT[128+k], l2W[k*64 + l], a);
    sT[256 + l] = a;
  }
  __syncthreads();
  for (int base = 0; base < 6; base += 2) {            // 5 heads L1: [320..480)
    const int hh = base + (l >> 5), j = l & 31;
    if (hh < 5) {
      const float* Wp = (hh==0) ? f1 : (hh==1) ? s1 : (hh==2) ? e1 : (hh==3) ? t1W : v1W;
      float a = (hh==3) ? t1b[j] : (hh==4) ? v1b[j] : 0.0f;
      for (int k = 0; k < 64; ++k) a = fmaf(sT[256+k], Wp[k*32 + j], a);
      sT[320 + hh*32 + j] = (a > 0.0f) ? a : 0.1f*a;
    }
  }
  __syncthreads();
  if (l < 56) {                                        // out1: [480..536)
    float a = 0.0f;
    for (int k = 0; k < 32; ++k) a = fmaf(sT[320+k], f2[k*56 + l], a);
    sT[480 + l] = a;
  }
  if (l < 56) {                                        // out2: [536..592)
    float a = 0.0f;
    for (int k = 0; k < 32; ++k) a = fmaf(sT[352+k], s2[k*56 + l], a);
    sT[536 + l] = a;
  }
  if (l < 3) {                                         // oute: [592..595)
    float a = 0.0f;
    for (int k = 0; k < 32; ++k) a = fmaf(sT[384+k], e2[k*3 + l], a);
    sT[592 + l] = a;
  }
  if (l < 2) {                                         // outs: [595..597)
    float a = t2b[l];
    for (int k = 0; k < 32; ++k) a = fmaf(sT[416+k], t2W[k*2 + l], a);
    sT[595 + l] = a;
  }
  if (l < 16) {                                        // v2h: [600..616)
    float a = v2b[l];
    for (int k = 0; k < 32; ++k) a = fmaf(sT[448+k], v2W[k*16 + l], a);
    sT[600 + l] = (a > 0.0f) ? a : 0.1f*a;
  }
  __syncthreads();
  if (l == 0) {                                        // value: [616]
    float a = v3b[0];
    for (int k = 0; k < 16; ++k) a = fmaf(sT[600+k], v3W[k], a);
    sT[616] = a;
  }
  __syncthreads();

  {
    const int m = l;
    const bool inb = (m < MD);
    const bool ex  = inb && (sNi[m] > 0) && (m < NN);
    const size_t ob = (size_t)b * 118;
    float lg1 = inb ? (sT[480+m] + (ex ? 0.0f : -10000.0f)) : -INFINITY;
    float mv = lg1; int mi = inb ? m : 1000;
    #pragma unroll
    for (int off = 32; off > 0; off >>= 1) {
      const float ov = __shfl_down(mv, off);
      const int   oi = __shfl_down(mi, off);
      if (ov > mv || (ov == mv && oi < mi)) { mv = ov; mi = oi; }
    }
    mv = __shfl(mv, 0);
    const int first = __shfl(mi, 0);
    float ev = inb ? __expf(lg1 - mv) : 0.0f;
    float sum1 = ev;
    #pragma unroll
    for (int off = 32; off > 0; off >>= 1) sum1 += __shfl_down(sum1, off);
    sum1 = rcp_f(__shfl(sum1, 0));
    if (inb) out[ob + m] = ev * sum1;
    const bool m2 = inb && ((ex || m >= NN) && (m != first));
    float lg2 = inb ? (sT[536+m] + (m2 ? 0.0f : -10000.0f)) : -INFINITY;
    float mv2 = lg2;
    #pragma unroll
    for (int off = 32; off > 0; off >>= 1) mv2 = fmaxf(mv2, __shfl_down(mv2, off));
    mv2 = __shfl(mv2, 0);
    float ev2 = inb ? __expf(lg2 - mv2) : 0.0f;
    float sum2 = ev2;
    #pragma unroll
    for (int off = 32; off > 0; off >>= 1) sum2 += __shfl_down(sum2, off);
    sum2 = rcp_f(__shfl(sum2, 0));
    if (inb) out[ob + 56 + m] = ev2 * sum2;
    if (m < 3) {
      const float x0 = sT[592], x1 = sT[593], x2 = sT[594];
      const float mx = fmaxf(x0, fmaxf(x1, x2));
      const float q0 = __expf(x0-mx), q1 = __expf(x1-mx), q2 = __expf(x2-mx);
      out[ob + 112 + m] = ((m==0) ? q0 : (m==1) ? q1 : q2) / (q0+q1+q2);
    }
    if (m < 2) {
      const float x0 = sT[595], x1 = sT[596];
      const float mx = fmaxf(x0, x1);
      const float q0 = __expf(x0-mx), q1 = __expf(x1-mx);
      out[ob + 115 + m] = ((m==0) ? q0 : q1) / (q0+q1);
    }
    if (m == 0) out[ob + 117] = sT[616];
  }
}

extern "C" void kernel_launch(void* const* d_in, const int* in_sizes, int n_in,
                              void* d_out, int out_size, void* d_ws, size_t ws_size,
                              hipStream_t stream) {
  (void)n_in; (void)out_size;
  const int B = in_sizes[0] / MD;
  const bool split = (ws_size >= (size_t)B * 128 * sizeof(float));
  float* gsumW = split ? (float*)d_ws : nullptr;

  policy_fwd<<<dim3(B), dim3(256), 0, stream>>>(
      (const int*)d_in[0],  (const float*)d_in[1],
      (const float*)d_in[2],  (const float*)d_in[3],
      (const float*)d_in[4],  (const float*)d_in[5],
      (const float*)d_in[6],  (const float*)d_in[7],
      (const float*)d_in[8],  (const float*)d_in[9],
      (const float*)d_in[10], (const float*)d_in[11],
      (const float*)d_in[12], (const float*)d_in[13],
      (const float*)d_in[14], (const float*)d_in[15],
      (const float*)d_in[16], (const float*)d_in[17],
      (const float*)d_in[18], (const float*)d_in[19],
      (const float*)d_in[20], (const float*)d_in[21],
      (const float*)d_in[22], (const float*)d_in[23],
      (const float*)d_in[24], (const float*)d_in[25],
      (const float*)d_in[26], (const float*)d_in[27],
      (const float*)d_in[28], (const float*)d_in[29],
      gsumW, (float*)d_out);

  if (split) {
    policy_tail<<<dim3(B), dim3(64), 0, stream>>>(
        (const int*)d_in[0], (const float*)gsumW,
        (const float*)d_in[10], (const float*)d_in[11],
        (const float*)d_in[12], (const float*)d_in[13],
        (const float*)d_in[14], (const float*)d_in[15],
        (const float*)d_in[16], (const float*)d_in[17],
        (const float*)d_in[18], (const float*)d_in[19],
        (const float*)d_in[20], (const float*)d_in[21],
        (const float*)d_in[22], (const float*)d_in[23],
        (const float*)d_in[24], (const float*)d_in[25],
        (const float*)d_in[26], (const float*)d_in[27],
        (const float*)d_in[28], (const float*)d_in[29],
        (float*)d_out);
  }
}

// Round 8
// 4986.989 us; speedup vs baseline: 1.8349x; 1.5476x over previous
//
#include <hip/hip_runtime.h>
#include <math.h>

#define NN 48
#define MD 56

typedef float f32x2 __attribute__((ext_vector_type(2)));

#if __has_builtin(__builtin_elementwise_fma)
#define PKFMA(A,B,C) __builtin_elementwise_fma(A,B,C)
#else
__device__ __forceinline__ f32x2 PKFMA(f32x2 a, f32x2 b, f32x2 c){
  f32x2 r; r.x = fmaf(a.x,b.x,c.x); r.y = fmaf(a.y,b.y,c.y); return r;
}
#endif
#define ELEM(v,u) ((u)==0 ? (v).x : (u)==1 ? (v).y : (u)==2 ? (v).z : (v).w)

__device__ __forceinline__ float rcp_f(float x){
#if __has_builtin(__builtin_amdgcn_rcpf)
  return __builtin_amdgcn_rcpf(x);
#else
  return 1.0f/x;
#endif
}

// ---------------- main kernel: deg/A build + M1..M4 + gsum ----------------
// One block per item; 256 threads; LDS ~40KB (4 blocks/CU if VGPR<=128).
// __launch_bounds__(256,2): compiler VGPR cap ~128 (cap ~= 256/minwaves —
// R6/R7 showed (256,4) caps at 64 and spills to scratch catastrophically).
// All fp chains bit-identical to R5/R7 (packed fma = same fp32 ops, same order).
__global__ __launch_bounds__(256, 2)
void policy_fwd(const int* __restrict__ Nmat, const float* __restrict__ adj,
                const float* __restrict__ W1, const float* __restrict__ b1,
                const float* __restrict__ W2, const float* __restrict__ b2,
                const float* __restrict__ agg_sW, const float* __restrict__ agg_sb,
                const float* __restrict__ agg_tW, const float* __restrict__ agg_tb,
                const float* __restrict__ l1W, const float* __restrict__ l1b,
                const float* __restrict__ l2W, const float* __restrict__ l2b,
                const float* __restrict__ f1, const float* __restrict__ f2,
                const float* __restrict__ s1, const float* __restrict__ s2,
                const float* __restrict__ e1, const float* __restrict__ e2,
                const float* __restrict__ t1W, const float* __restrict__ t1b,
                const float* __restrict__ t2W, const float* __restrict__ t2b,
                const float* __restrict__ v1W, const float* __restrict__ v1b,
                const float* __restrict__ v2W, const float* __restrict__ v2b,
                const float* __restrict__ v3W, const float* __restrict__ v3b,
                float* __restrict__ gsumW,    // non-null => tail kernel handles rest
                float* __restrict__ out)
{
  __shared__ __align__(16) float sA[NN*48];    // A row-major, stride 48
  __shared__ __align__(16) float sHB[3264];    // h col-block / h_out / (fallback sT); deg at [3104..3248)
  __shared__ __align__(16) float sH2[3264];    // h2 (48x68); later M4 ch1 partials
  __shared__ __align__(16) float sEP[1280];    // embT[9][128]; later ch0 partials + gsum[128]
  __shared__ int   sNi[MD];

  const int b   = blockIdx.x;
  const int tid = threadIdx.x;
  const float* adjB = adj + (size_t)b * (3*NN*NN);
  float* sDeg = &sHB[3104];

  if (tid < MD) sNi[tid] = Nmat[b*MD + tid];

  // ---- degrees (exact div) ----
  {
    const int lane = tid & 15, grp = tid >> 4;
    for (int p = 0; p < 9; ++p) {
      const int row = p*16 + grp;
      const float* rp = adjB + row*NN;
      float s = rp[lane] + rp[lane+16] + rp[lane+32];
      s += __shfl_down(s, 8, 16);
      s += __shfl_down(s, 4, 16);
      s += __shfl_down(s, 2, 16);
      s += __shfl_down(s, 1, 16);
      if (lane == 0) sDeg[row] = 1.0f/(s + 1.0f);
    }
  }
  for (int o = tid; o < 1152; o += 256) sEP[o] = W1[o] + b1[o & 127];
  __syncthreads();

  // ---- A ----
  for (int o = tid; o < NN*NN; o += 256) {
    const int i = o / NN, j = o - i*NN;
    const float v = adjB[i*NN + j]          * sDeg[i]
                  + adjB[(NN + i)*NN + j]   * sDeg[NN + i]
                  + adjB[(2*NN + i)*NN + j] * sDeg[2*NN + i];
    sA[i*48 + j] = v;
  }
  __syncthreads();

  const int i2 = (tid >> 4)*3, d2 = (tid & 15)*4;

  // ---- M1+M2 fused, two 64-col rounds; chains identical to R5 ----
  f32x2 q0a={0.f,0.f}, q0b={0.f,0.f}, q1a={0.f,0.f}, q1b={0.f,0.f},
        q2a={0.f,0.f}, q2b={0.f,0.f};                 // h2 accumulators (persistent)
  #pragma unroll
  for (int r = 0; r < 2; ++r) {
    const int dg = r*64 + d2;
    // ---- M1: h(i2..i2+2, dg..dg+3); A via ds_read_b128, packed fma ----
    {
      f32x2 p0a={0.f,0.f}, p0b={0.f,0.f}, p1a={0.f,0.f}, p1b={0.f,0.f},
            p2a={0.f,0.f}, p2b={0.f,0.f};
      for (int c = 0; c < 12; ++c) {
        const float4 av0 = *(const float4*)&sA[(i2  )*48 + c*4];
        const float4 av1 = *(const float4*)&sA[(i2+1)*48 + c*4];
        const float4 av2 = *(const float4*)&sA[(i2+2)*48 + c*4];
        #pragma unroll
        for (int u = 0; u < 4; ++u) {
          const float4 bv = *(const float4*)&sEP[sNi[c*4+u]*128 + dg];
          f32x2 bl; bl.x = bv.x; bl.y = bv.y;
          f32x2 bh; bh.x = bv.z; bh.y = bv.w;
          f32x2 A0; A0.x = A0.y = ELEM(av0,u);
          f32x2 A1; A1.x = A1.y = ELEM(av1,u);
          f32x2 A2; A2.x = A2.y = ELEM(av2,u);
          p0a = PKFMA(A0, bl, p0a); p0b = PKFMA(A0, bh, p0b);
          p1a = PKFMA(A1, bl, p1a); p1b = PKFMA(A1, bh, p1b);
          p2a = PKFMA(A2, bl, p2a); p2b = PKFMA(A2, bh, p2b);
        }
      }
      const float4 rv0 = *(const float4*)&sEP[sNi[i2  ]*128 + dg];
      const float4 rv1 = *(const float4*)&sEP[sNi[i2+1]*128 + dg];
      const float4 rv2 = *(const float4*)&sEP[sNi[i2+2]*128 + dg];
      float4 o0, o1, o2;
      o0.x = tanhf(p0a.x + rv0.x); o0.y = tanhf(p0a.y + rv0.y);
      o0.z = tanhf(p0b.x + rv0.z); o0.w = tanhf(p0b.y + rv0.w);
      o1.x = tanhf(p1a.x + rv1.x); o1.y = tanhf(p1a.y + rv1.y);
      o1.z = tanhf(p1b.x + rv1.z); o1.w = tanhf(p1b.y + rv1.w);
      o2.x = tanhf(p2a.x + rv2.x); o2.y = tanhf(p2a.y + rv2.y);
      o2.z = tanhf(p2b.x + rv2.z); o2.w = tanhf(p2b.y + rv2.w);
      *(float4*)&sHB[(i2  )*68 + d2] = o0;
      *(float4*)&sHB[(i2+1)*68 + d2] = o1;
      *(float4*)&sHB[(i2+2)*68 + d2] = o2;
    }
    __syncthreads();
    // ---- M2 accumulate: h2 += h[:,blk] @ W2[blk,:] ----
    {
      const float* W2r = W2 + r*4096;
      for (int c = 0; c < 16; ++c) {
        const float4 av0 = *(const float4*)&sHB[(i2  )*68 + c*4];
        const float4 av1 = *(const float4*)&sHB[(i2+1)*68 + c*4];
        const float4 av2 = *(const float4*)&sHB[(i2+2)*68 + c*4];
        #pragma unroll
        for (int u = 0; u < 4; ++u) {
          const float4 wv = *(const float4*)&W2r[(c*4+u)*64 + d2];
          f32x2 bl; bl.x = wv.x; bl.y = wv.y;
          f32x2 bh; bh.x = wv.z; bh.y = wv.w;
          f32x2 A0; A0.x = A0.y = ELEM(av0,u);
          f32x2 A1; A1.x = A1.y = ELEM(av1,u);
          f32x2 A2; A2.x = A2.y = ELEM(av2,u);
          q0a = PKFMA(A0, bl, q0a); q0b = PKFMA(A0, bh, q0b);
          q1a = PKFMA(A1, bl, q1a); q1b = PKFMA(A1, bh, q1b);
          q2a = PKFMA(A2, bl, q2a); q2b = PKFMA(A2, bh, q2b);
        }
      }
    }
    __syncthreads();
  }
  {
    const float4 bb = *(const float4*)&b2[d2];
    float4 o0, o1, o2;
    o0.x = q0a.x + bb.x; o0.y = q0a.y + bb.y; o0.z = q0b.x + bb.z; o0.w = q0b.y + bb.w;
    o1.x = q1a.x + bb.x; o1.y = q1a.y + bb.y; o1.z = q1b.x + bb.z; o1.w = q1b.y + bb.w;
    o2.x = q2a.x + bb.x; o2.y = q2a.y + bb.y; o2.z = q2b.x + bb.z; o2.w = q2b.y + bb.w;
    *(float4*)&sH2[(i2  )*68 + d2] = o0;
    *(float4*)&sH2[(i2+1)*68 + d2] = o1;
    *(float4*)&sH2[(i2+2)*68 + d2] = o2;
  }
  __syncthreads();

  // ---- M3: h_out = tanh(A@h2 + h2) -> sHB ----
  {
    f32x2 p0a={0.f,0.f}, p0b={0.f,0.f}, p1a={0.f,0.f}, p1b={0.f,0.f},
          p2a={0.f,0.f}, p2b={0.f,0.f};
    for (int c = 0; c < 12; ++c) {
      const float4 av0 = *(const float4*)&sA[(i2  )*48 + c*4];
      const float4 av1 = *(const float4*)&sA[(i2+1)*48 + c*4];
      const float4 av2 = *(const float4*)&sA[(i2+2)*48 + c*4];
      #pragma unroll
      for (int u = 0; u < 4; ++u) {
        const float4 bv = *(const float4*)&sH2[(c*4+u)*68 + d2];
        f32x2 bl; bl.x = bv.x; bl.y = bv.y;
        f32x2 bh; bh.x = bv.z; bh.y = bv.w;
        f32x2 A0; A0.x = A0.y = ELEM(av0,u);
        f32x2 A1; A1.x = A1.y = ELEM(av1,u);
        f32x2 A2; A2.x = A2.y = ELEM(av2,u);
        p0a = PKFMA(A0, bl, p0a); p0b = PKFMA(A0, bh, p0b);
        p1a = PKFMA(A1, bl, p1a); p1b = PKFMA(A1, bh, p1b);
        p2a = PKFMA(A2, bl, p2a); p2b = PKFMA(A2, bh, p2b);
      }
    }
    const float4 rv0 = *(const float4*)&sH2[(i2  )*68 + d2];
    const float4 rv1 = *(const float4*)&sH2[(i2+1)*68 + d2];
    const float4 rv2 = *(const float4*)&sH2[(i2+2)*68 + d2];
    float4 o0, o1, o2;
    o0.x = tanhf(p0a.x + rv0.x); o0.y = tanhf(p0a.y + rv0.y);
    o0.z = tanhf(p0b.x + rv0.z); o0.w = tanhf(p0b.y + rv0.w);
    o1.x = tanhf(p1a.x + rv1.x); o1.y = tanhf(p1a.y + rv1.y);
    o1.z = tanhf(p1b.x + rv1.z); o1.w = tanhf(p1b.y + rv1.w);
    o2.x = tanhf(p2a.x + rv2.x); o2.y = tanhf(p2a.y + rv2.y);
    o2.z = tanhf(p2b.x + rv2.z); o2.w = tanhf(p2b.y + rv2.w);
    *(float4*)&sHB[(i2  )*68 + d2] = o0;
    *(float4*)&sHB[(i2+1)*68 + d2] = o1;
    *(float4*)&sHB[(i2+2)*68 + d2] = o2;
  }
  __syncthreads();   // h_out in sHB; sH2, sEP dead

  // ---- M4: TWO channel passes (24 live acc VGPRs each, not 48).
  // Per-output k-chain and epilogue order identical to R5/R7 single-pass.
  #pragma unroll
  for (int ch = 0; ch < 2; ++ch) {
    f32x2 sa0={0.f,0.f}, sb0={0.f,0.f}, sa1={0.f,0.f}, sb1={0.f,0.f},
          sa2={0.f,0.f}, sb2={0.f,0.f};
    f32x2 ta0={0.f,0.f}, tb0={0.f,0.f}, ta1={0.f,0.f}, tb1={0.f,0.f},
          ta2={0.f,0.f}, tb2={0.f,0.f};
    const float* Sp = agg_sW + ch*64 + d2;
    const float* Tp = agg_tW + ch*64 + d2;
    for (int c = 0; c < 16; ++c) {
      const float4 av0 = *(const float4*)&sHB[(i2  )*68 + c*4];
      const float4 av1 = *(const float4*)&sHB[(i2+1)*68 + c*4];
      const float4 av2 = *(const float4*)&sHB[(i2+2)*68 + c*4];
      #pragma unroll
      for (int u = 0; u < 4; ++u) {
        const int k = c*4 + u;
        const float4 bs = *(const float4*)&Sp[k*128];
        const float4 bt = *(const float4*)&Tp[k*128];
        f32x2 sl; sl.x = bs.x; sl.y = bs.y;
        f32x2 sh; sh.x = bs.z; sh.y = bs.w;
        f32x2 tl; tl.x = bt.x; tl.y = bt.y;
        f32x2 th; th.x = bt.z; th.y = bt.w;
        f32x2 A0; A0.x = A0.y = ELEM(av0,u);
        f32x2 A1; A1.x = A1.y = ELEM(av1,u);
        f32x2 A2; A2.x = A2.y = ELEM(av2,u);
        sa0 = PKFMA(A0, sl, sa0); sb0 = PKFMA(A0, sh, sb0);
        sa1 = PKFMA(A1, sl, sa1); sb1 = PKFMA(A1, sh, sb1);
        sa2 = PKFMA(A2, sl, sa2); sb2 = PKFMA(A2, sh, sb2);
        ta0 = PKFMA(A0, tl, ta0); tb0 = PKFMA(A0, th, tb0);
        ta1 = PKFMA(A1, tl, ta1); tb1 = PKFMA(A1, th, tb1);
        ta2 = PKFMA(A2, tl, ta2); tb2 = PKFMA(A2, th, tb2);
      }
    }
    // epilogue (order identical to R5: acc + gather + bias; ii ascending)
    float p[4] = {0.f,0.f,0.f,0.f};
    const float4 bsb = *(const float4*)&agg_sb[ch*64 + d2];
    const float4 btb = *(const float4*)&agg_tb[ch*64 + d2];
    #pragma unroll
    for (int ii = 0; ii < 3; ++ii) {
      const f32x2 sa = (ii==0) ? sa0 : (ii==1) ? sa1 : sa2;
      const f32x2 sb = (ii==0) ? sb0 : (ii==1) ? sb1 : sb2;
      const f32x2 ta = (ii==0) ? ta0 : (ii==1) ? ta1 : ta2;
      const f32x2 tb = (ii==0) ? tb0 : (ii==1) ? tb1 : tb2;
      const int t = sNi[i2+ii];
      const float* gs = &agg_sW[(64 + t)*128 + ch*64 + d2];
      const float* gt = &agg_tW[(64 + t)*128 + ch*64 + d2];
      #pragma unroll
      for (int dd = 0; dd < 4; ++dd) {
        const float as = (dd==0)?sa.x:(dd==1)?sa.y:(dd==2)?sb.x:sb.y;
        const float at = (dd==0)?ta.x:(dd==1)?ta.y:(dd==2)?tb.x:tb.y;
        const float sg = 1.0f/(1.0f + expf(-(as + gs[dd] + ELEM(bsb,dd))));
        const float tg = tanhf(at + gt[dd] + ELEM(btb,dd));
        p[dd] = fmaf(sg, tg, p[dd]);
      }
    }
    const int grp = tid >> 4;
    if (ch == 0) *(float4*)&sEP[grp*64 + d2] = *(float4*)p;   // ch0 partials
    else         *(float4*)&sH2[grp*64 + d2] = *(float4*)p;   // ch1 partials
  }
  __syncthreads();
  if (tid < 64) {
    float s = 0.0f;
    #pragma unroll
    for (int g = 0; g < 16; ++g) s += sEP[g*64 + tid];
    sEP[1024 + tid] = s;
  } else if (tid < 128) {
    const int m = tid - 64;
    float s = 0.0f;
    #pragma unroll
    for (int g = 0; g < 16; ++g) s += sH2[g*64 + m];
    sEP[1024 + 64 + m] = s;
  }
  __syncthreads();

  if (gsumW != nullptr) {
    if (tid < 128) gsumW[(size_t)b*128 + tid] = sEP[1024 + tid];
    return;
  }

  // ---------------- fallback in-kernel tail (R5 verbatim) ----------------
  float* sT = sHB;
  const float* sGsum = &sEP[1024];
  if (tid < 128) sT[tid + 1024] = tanhf(sGsum[tid]);
  __syncthreads();
  if (tid < 128) {
    float a = l1b[tid];
    for (int k = 0; k < 128; ++k) a = fmaf(sT[1024+k], l1W[k*128 + tid], a);
    sT[1152 + tid] = a;
  }
  __syncthreads();
  if (tid < 64) {
    float a = l2b[tid];
    for (int k = 0; k < 128; ++k) a = fmaf(sT[1152+k], l2W[k*64 + tid], a);
    sT[1280 + tid] = a;
  }
  __syncthreads();
  if (tid < 160) {
    const int hh = tid >> 5, j = tid & 31;
    const float* Wp = (hh==0) ? f1 : (hh==1) ? s1 : (hh==2) ? e1 : (hh==3) ? t1W : v1W;
    float a = (hh==3) ? t1b[j] : (hh==4) ? v1b[j] : 0.0f;
    for (int k = 0; k < 64; ++k) a = fmaf(sT[1280+k], Wp[k*32 + j], a);
    sT[1344 + tid] = (a > 0.0f) ? a : 0.1f*a;
  }
  __syncthreads();
  if (tid < 56) {
    float a = 0.0f;
    for (int k = 0; k < 32; ++k) a = fmaf(sT[1344+k], f2[k*56 + tid], a);
    sT[1504 + tid] = a;
  } else if (tid < 112) {
    const int m = tid - 56; float a = 0.0f;
    for (int k = 0; k < 32; ++k) a = fmaf(sT[1376+k], s2[k*56 + m], a);
    sT[1560 + m] = a;
  } else if (tid < 115) {
    const int m = tid - 112; float a = 0.0f;
    for (int k = 0; k < 32; ++k) a = fmaf(sT[1408+k], e2[k*3 + m], a);
    sT[1616 + m] = a;
  } else if (tid < 117) {
    const int m = tid - 115; float a = t2b[m];
    for (int k = 0; k < 32; ++k) a = fmaf(sT[1440+k], t2W[k*2 + m], a);
    sT[1619 + m] = a;
  } else if (tid < 133) {
    const int m = tid - 117; float a = v2b[m];
    for (int k = 0; k < 32; ++k) a = fmaf(sT[1472+k], v2W[k*16 + m], a);
    sT[1624 + m] = (a > 0.0f) ? a : 0.1f*a;
  }
  __syncthreads();
  if (tid == 0) {
    float a = v3b[0];
    for (int k = 0; k < 16; ++k) a = fmaf(sT[1624+k], v3W[k], a);
    sT[1640] = a;
  }
  __syncthreads();
  if (tid < 64) {
    const int m = tid;
    const bool inb = (m < MD);
    const bool ex  = inb && (sNi[m] > 0) && (m < NN);
    const size_t ob = (size_t)b * 118;
    float lg1 = inb ? (sT[1504+m] + (ex ? 0.0f : -10000.0f)) : -INFINITY;
    float mv = lg1; int mi = inb ? m : 1000;
    #pragma unroll
    for (int off = 32; off > 0; off >>= 1) {
      const float ov = __shfl_down(mv, off);
      const int   oi = __shfl_down(mi, off);
      if (ov > mv || (ov == mv && oi < mi)) { mv = ov; mi = oi; }
    }
    mv = __shfl(mv, 0);
    const int first = __shfl(mi, 0);
    float ev = inb ? __expf(lg1 - mv) : 0.0f;
    float sum1 = ev;
    #pragma unroll
    for (int off = 32; off > 0; off >>= 1) sum1 += __shfl_down(sum1, off);
    sum1 = rcp_f(__shfl(sum1, 0));
    if (inb) out[ob + m] = ev * sum1;
    const bool m2 = inb && ((ex || m >= NN) && (m != first));
    float lg2 = inb ? (sT[1560+m] + (m2 ? 0.0f : -10000.0f)) : -INFINITY;
    float mv2 = lg2;
    #pragma unroll
    for (int off = 32; off > 0; off >>= 1) mv2 = fmaxf(mv2, __shfl_down(mv2, off));
    mv2 = __shfl(mv2, 0);
    float ev2 = inb ? __expf(lg2 - mv2) : 0.0f;
    float sum2 = ev2;
    #pragma unroll
    for (int off = 32; off > 0; off >>= 1) sum2 += __shfl_down(sum2, off);
    sum2 = rcp_f(__shfl(sum2, 0));
    if (inb) out[ob + 56 + m] = ev2 * sum2;
    if (m < 3) {
      const float x0 = sT[1616], x1 = sT[1617], x2 = sT[1618];
      const float mx = fmaxf(x0, fmaxf(x1, x2));
      const float q0 = __expf(x0-mx), q1 = __expf(x1-mx), q2 = __expf(x2-mx);
      out[ob + 112 + m] = ((m==0) ? q0 : (m==1) ? q1 : q2) / (q0+q1+q2);
    }
    if (m < 2) {
      const float x0 = sT[1619], x1 = sT[1620];
      const float mx = fmaxf(x0, x1);
      const float q0 = __expf(x0-mx), q1 = __expf(x1-mx);
      out[ob + 115 + m] = ((m==0) ? q0 : q1) / (q0+q1);
    }
    if (m == 0) out[ob + 117] = sT[1640];
  }
}

// ---------------- tail kernel: 1 wave per item ----------------
__global__ __launch_bounds__(64, 8)
void policy_tail(const int* __restrict__ Nmat, const float* __restrict__ gsumW,
                 const float* __restrict__ l1W, const float* __restrict__ l1b,
                 const float* __restrict__ l2W, const float* __restrict__ l2b,
                 const float* __restrict__ f1, const float* __restrict__ f2,
                 const float* __restrict__ s1, const float* __restrict__ s2,
                 const float* __restrict__ e1, const float* __restrict__ e2,
                 const float* __restrict__ t1W, const float* __restrict__ t1b,
                 const float* __restrict__ t2W, const float* __restrict__ t2b,
                 const float* __restrict__ v1W, const float* __restrict__ v1b,
                 const float* __restrict__ v2W, const float* __restrict__ v2b,
                 const float* __restrict__ v3W, const float* __restrict__ v3b,
                 float* __restrict__ out)
{
  __shared__ float sT[648];
  __shared__ int sNi[MD];
  const int b = blockIdx.x, l = threadIdx.x;

  if (l < MD) sNi[l] = Nmat[b*MD + l];
  sT[l]      = tanhf(gsumW[(size_t)b*128 + l]);       // g
  sT[64 + l] = tanhf(gsumW[(size_t)b*128 + 64 + l]);
  __syncthreads();
  #pragma unroll
  for (int h = 0; h < 2; ++h) {                        // a1: [128..256)
    const int j = h*64 + l;
    float a = l1b[j];
    for (int k = 0; k < 128; ++k) a = fmaf(sT[k], l1W[k*128 + j], a);
    sT[128 + j] = a;
  }
  __syncthreads();
  {                                                    // hfeat: [256..320)
    float a = l2b[l];
    for (int k = 0; k < 128; ++k) a = fmaf(sT[128+k], l2W[k*64 + l], a);
    sT[256 + l] = a;
  }
  __syncthreads();
  for (int base = 0; base < 6; base += 2) {            // 5 heads L1: [320..480)
    const int hh = base + (l >> 5), j = l & 31;
    if (hh < 5) {
      const float* Wp = (hh==0) ? f1 : (hh==1) ? s1 : (hh==2) ? e1 : (hh==3) ? t1W : v1W;
      float a = (hh==3) ? t1b[j] : (hh==4) ? v1b[j] : 0.0f;
      for (int k = 0; k < 64; ++k) a = fmaf(sT[256+k], Wp[k*32 + j], a);
      sT[320 + hh*32 + j] = (a > 0.0f) ? a : 0.1f*a;
    }
  }
  __syncthreads();
  if (l < 56) {                                        // out1: [480..536)
    float a = 0.0f;
    for (int k = 0; k < 32; ++k) a = fmaf(sT[320+k], f2[k*56 + l], a);
    sT[480 + l] = a;
  }
  if (l < 56) {                                        // out2: [536..592)
    float a = 0.0f;
    for (int k = 0; k < 32; ++k) a = fmaf(sT[352+k], s2[k*56 + l], a);
    sT[536 + l] = a;
  }
  if (l < 3) {                                         // oute: [592..595)
    float a = 0.0f;
    for (int k = 0; k < 32; ++k) a = fmaf(sT[384+k], e2[k*3 + l], a);
    sT[592 + l] = a;
  }
  if (l < 2) {                                         // outs: [595..597)
    float a = t2b[l];
    for (int k = 0; k < 32; ++k) a = fmaf(sT[416+k], t2W[k*2 + l], a);
    sT[595 + l] = a;
  }
  if (l < 16) {                                        // v2h: [600..616)
    float a = v2b[l];
    for (int k = 0; k < 32; ++k) a = fmaf(sT[448+k], v2W[k*16 + l], a);
    sT[600 + l] = (a > 0.0f) ? a : 0.1f*a;
  }
  __syncthreads();
  if (l == 0) {                                        // value: [616]
    float a = v3b[0];
    for (int k = 0; k < 16; ++k) a = fmaf(sT[600+k], v3W[k], a);
    sT[616] = a;
  }
  __syncthreads();

  {
    const int m = l;
    const bool inb = (m < MD);
    const bool ex  = inb && (sNi[m] > 0) && (m < NN);
    const size_t ob = (size_t)b * 118;
    float lg1 = inb ? (sT[480+m] + (ex ? 0.0f : -10000.0f)) : -INFINITY;
    float mv = lg1; int mi = inb ? m : 1000;
    #pragma unroll
    for (int off = 32; off > 0; off >>= 1) {
      const float ov = __shfl_down(mv, off);
      const int   oi = __shfl_down(mi, off);
      if (ov > mv || (ov == mv && oi < mi)) { mv = ov; mi = oi; }
    }
    mv = __shfl(mv, 0);
    const int first = __shfl(mi, 0);
    float ev = inb ? __expf(lg1 - mv) : 0.0f;
    float sum1 = ev;
    #pragma unroll
    for (int off = 32; off > 0; off >>= 1) sum1 += __shfl_down(sum1, off);
    sum1 = rcp_f(__shfl(sum1, 0));
    if (inb) out[ob + m] = ev * sum1;
    const bool m2 = inb && ((ex || m >= NN) && (m != first));
    float lg2 = inb ? (sT[536+m] + (m2 ? 0.0f : -10000.0f)) : -INFINITY;
    float mv2 = lg2;
    #pragma unroll
    for (int off = 32; off > 0; off >>= 1) mv2 = fmaxf(mv2, __shfl_down(mv2, off));
    mv2 = __shfl(mv2, 0);
    float ev2 = inb ? __expf(lg2 - mv2) : 0.0f;
    float sum2 = ev2;
    #pragma unroll
    for (int off = 32; off > 0; off >>= 1) sum2 += __shfl_down(sum2, off);
    sum2 = rcp_f(__shfl(sum2, 0));
    if (inb) out[ob + 56 + m] = ev2 * sum2;
    if (m < 3) {
      const float x0 = sT[592], x1 = sT[593], x2 = sT[594];
      const float mx = fmaxf(x0, fmaxf(x1, x2));
      const float q0 = __expf(x0-mx), q1 = __expf(x1-mx), q2 = __expf(x2-mx);
      out[ob + 112 + m] = ((m==0) ? q0 : (m==1) ? q1 : q2) / (q0+q1+q2);
    }
    if (m < 2) {
      const float x0 = sT[595], x1 = sT[596];
      const float mx = fmaxf(x0, x1);
      const float q0 = __expf(x0-mx), q1 = __expf(x1-mx);
      out[ob + 115 + m] = ((m==0) ? q0 : q1) / (q0+q1);
    }
    if (m == 0) out[ob + 117] = sT[616];
  }
}

extern "C" void kernel_launch(void* const* d_in, const int* in_sizes, int n_in,
                              void* d_out, int out_size, void* d_ws, size_t ws_size,
                              hipStream_t stream) {
  (void)n_in; (void)out_size;
  const int B = in_sizes[0] / MD;
  const bool split = (ws_size >= (size_t)B * 128 * sizeof(float));
  float* gsumW = split ? (float*)d_ws : nullptr;

  policy_fwd<<<dim3(B), dim3(256), 0, stream>>>(
      (const int*)d_in[0],  (const float*)d_in[1],
      (const float*)d_in[2],  (const float*)d_in[3],
      (const float*)d_in[4],  (const float*)d_in[5],
      (const float*)d_in[6],  (const float*)d_in[7],
      (const float*)d_in[8],  (const float*)d_in[9],
      (const float*)d_in[10], (const float*)d_in[11],
      (const float*)d_in[12], (const float*)d_in[13],
      (const float*)d_in[14], (const float*)d_in[15],
      (const float*)d_in[16], (const float*)d_in[17],
      (const float*)d_in[18], (const float*)d_in[19],
      (const float*)d_in[20], (const float*)d_in[21],
      (const float*)d_in[22], (const float*)d_in[23],
      (const float*)d_in[24], (const float*)d_in[25],
      (const float*)d_in[26], (const float*)d_in[27],
      (const float*)d_in[28], (const float*)d_in[29],
      gsumW, (float*)d_out);

  if (split) {
    policy_tail<<<dim3(B), dim3(64), 0, stream>>>(
        (const int*)d_in[0], (const float*)gsumW,
        (const float*)d_in[10], (const float*)d_in[11],
        (const float*)d_in[12], (const float*)d_in[13],
        (const float*)d_in[14], (const float*)d_in[15],
        (const float*)d_in[16], (const float*)d_in[17],
        (const float*)d_in[18], (const float*)d_in[19],
        (const float*)d_in[20], (const float*)d_in[21],
        (const float*)d_in[22], (const float*)d_in[23],
        (const float*)d_in[24], (const float*)d_in[25],
        (const float*)d_in[26], (const float*)d_in[27],
        (const float*)d_in[28], (const float*)d_in[29],
        (float*)d_out);
  }
}